// Round 2
// baseline (558.991 us; speedup 1.0000x reference)
//
#include <hip/hip_runtime.h>

#define IN_W 224
#define IMG_CH (224*224)        // 50176
#define IMG_SZ (3*IMG_CH)       // 150528
#define P1 37
#define P1SZ (P1*P1)            // 1369
#define P1_STRIDE 4108          // 3*1369 = 4107, +1 pad -> float4-aligned per image

// ---------------------------------------------------------------------------
// Kernel 1: conv1(3x3,s2) + maxpool3 + relu.
// Block = (band of 2 pooled rows, image). Stage 13 input rows x 224 x 3ch
// (34.9 KB) into LDS with coalesced float4, compute from LDS.
// Thread = (site, out-ch): 222 active threads, 243 FMA each.
// Output layout: [img][site][ch] (channel-minor) -> contiguous 888B store run.
// ---------------------------------------------------------------------------
__global__ __launch_bounds__(256, 4) void conv1_kernel(
    const float* __restrict__ nodes, const float* __restrict__ depths,
    const float* __restrict__ c1w, const float* __restrict__ c1b,
    const float* __restrict__ d1w, const float* __restrict__ d1b,
    float* __restrict__ pool1_ws)
{
    __shared__ __align__(16) float lds[3 * 13 * 224];   // 34944 B

    const int band = blockIdx.x;          // 0..18
    const int img  = blockIdx.y;          // 0..639
    const int t    = threadIdx.x;

    const float* in; const float* w1g; const float* b1g;
    if (img < 320) { in = nodes  + (size_t)img         * IMG_SZ; w1g = c1w; b1g = c1b; }
    else           { in = depths + (size_t)(img - 320) * IMG_SZ; w1g = d1w; b1g = d1b; }

    const int py0   = 2 * band;
    const int nsr   = (py0 + 1 < P1) ? 2 : 1;   // site rows in this band
    const int nrows = 6 * nsr + 1;              // 13 or 7 input rows
    const int row0  = 12 * band;

    // ---- stage: 2184 float4 (full band) via registers, coalesced ----
    float4 v[9];
    int    fi[9];
    bool   ok[9];
    #pragma unroll
    for (int i = 0; i < 9; ++i) {
        const int f  = t + i * 256;
        const int ch = f / (13 * 56);
        const int rr = (f / 56) % 13;
        const int cc = f % 56;
        const bool o = (f < 2184) && (rr < nrows);
        fi[i] = f; ok[i] = o;
        if (o) v[i] = *(const float4*)(in + ch * IMG_CH + (row0 + rr) * IN_W + cc * 4);
    }
    #pragma unroll
    for (int i = 0; i < 9; ++i)
        if (ok[i]) *(float4*)&lds[fi[i] * 4] = v[i];

    // per-thread weights for its out-channel
    const int c = t % 3, s = t / 3;
    float w[27];
    #pragma unroll
    for (int k = 0; k < 27; ++k) w[k] = w1g[c * 27 + k];
    const float bv = b1g[c];

    __syncthreads();

    // ---- compute ----
    const int nsites = nsr * 37;
    if (s < nsites) {
        const int dy = s / 37, px = s - dy * 37;
        float acc[9];
        #pragma unroll
        for (int q = 0; q < 9; ++q) acc[q] = bv;

        #pragma unroll
        for (int ic = 0; ic < 3; ++ic) {
            const float* base = &lds[(ic * 13 + 6 * dy) * 224 + 6 * px];
            #pragma unroll
            for (int r = 0; r < 7; ++r) {
                const float* rp = base + r * 224;       // 8B-aligned (even offs)
                const float2 a0 = *(const float2*)(rp);
                const float2 a1 = *(const float2*)(rp + 2);
                const float2 a2 = *(const float2*)(rp + 4);
                float row[7];
                row[0] = a0.x; row[1] = a0.y; row[2] = a1.x; row[3] = a1.y;
                row[4] = a2.x; row[5] = a2.y; row[6] = rp[6];
                #pragma unroll
                for (int ky = 0; ky < 3; ++ky) {
                    const int u = r - 2 * ky;           // compile-time after unroll
                    if (u < 0 || u > 2) continue;
                    #pragma unroll
                    for (int kx = 0; kx < 3; ++kx)
                        #pragma unroll
                        for (int vv = 0; vv < 3; ++vv)
                            acc[ky*3+kx] = fmaf(row[2*kx + vv],
                                                w[ic*9 + u*3 + vv],
                                                acc[ky*3+kx]);
                }
            }
        }
        float m = acc[0];
        #pragma unroll
        for (int q = 1; q < 9; ++q) m = fmaxf(m, acc[q]);
        // channel-minor: lanes t = 3*s + c write consecutive addresses
        pool1_ws[(size_t)img * P1_STRIDE + (py0 * 37 + s) * 3 + c] = fmaxf(m, 0.f);
    }
}

// ---------------------------------------------------------------------------
// Kernel 2: conv2(3->1,3x3,s2) + maxpool3 + relu + linear 36->6, per image.
// Stage pool1 image (16.4 KB) into LDS with coalesced float4, compute there.
// pool1 layout is [site][3] channel-minor.
// ---------------------------------------------------------------------------
__global__ __launch_bounds__(64) void conv2_kernel(
    const float* __restrict__ pool1_ws,
    const float* __restrict__ c2w, const float* __restrict__ c2b,
    const float* __restrict__ lw,  const float* __restrict__ lb,
    const float* __restrict__ d2w, const float* __restrict__ d2b,
    const float* __restrict__ dlw, const float* __restrict__ dlb,
    float* __restrict__ feat_ws, float* __restrict__ dfeat_ws)
{
    __shared__ __align__(16) float p1s[P1_STRIDE];   // 4108 floats
    __shared__ float pool2[36];
    const int img = blockIdx.x;
    const int t = threadIdx.x;
    const float *w2, *b2, *lwp, *lbp; float* outp;
    if (img < 320) { w2 = c2w; b2 = c2b; lwp = lw;  lbp = lb;  outp = feat_ws  + img * 6; }
    else           { w2 = d2w; b2 = d2b; lwp = dlw; lbp = dlb; outp = dfeat_ws + (img - 320) * 6; }

    const float4* src = (const float4*)(pool1_ws + (size_t)img * P1_STRIDE);
    #pragma unroll
    for (int i = 0; i < 17; ++i) {
        const int f = t + i * 64;
        if (f < P1_STRIDE / 4) ((float4*)p1s)[f] = src[f];
    }
    __syncthreads();

    if (t < 36) {
        const int qy = t / 6, qx = t - qy * 6;
        float acc[9];
        const float bvv = b2[0];
        #pragma unroll
        for (int q = 0; q < 9; ++q) acc[q] = bvv;
        #pragma unroll
        for (int r = 0; r < 7; ++r) {
            // 7 sites x 3 ch = 21 contiguous floats
            const float* rp = &p1s[((6 * qy + r) * 37 + 6 * qx) * 3];
            float buf[21];
            #pragma unroll
            for (int j = 0; j < 21; ++j) buf[j] = rp[j];
            #pragma unroll
            for (int ky = 0; ky < 3; ++ky) {
                const int u = r - 2 * ky;
                if (u < 0 || u > 2) continue;
                #pragma unroll
                for (int kx = 0; kx < 3; ++kx)
                    #pragma unroll
                    for (int vv = 0; vv < 3; ++vv)
                        #pragma unroll
                        for (int ic = 0; ic < 3; ++ic)
                            acc[ky*3+kx] = fmaf(buf[(2*kx + vv) * 3 + ic],
                                                w2[ic*9 + u*3 + vv],
                                                acc[ky*3+kx]);
            }
        }
        float m = acc[0];
        #pragma unroll
        for (int q = 1; q < 9; ++q) m = fmaxf(m, acc[q]);
        pool2[t] = fmaxf(m, 0.f);
    }
    __syncthreads();
    if (t < 6) {
        float sacc = lbp[t];
        #pragma unroll
        for (int k = 0; k < 36; ++k) sacc = fmaf(pool2[k], lwp[t*36 + k], sacc);
        outp[t] = sacc;
    }
}

// ---------------------------------------------------------------------------
// Head: message passing + fc1/fc2/fc3 (unchanged).
// ---------------------------------------------------------------------------
__global__ __launch_bounds__(256) void head_kernel(
    const float* __restrict__ pos, const float* __restrict__ attmap,
    const float* __restrict__ fmp_w, const float* __restrict__ fmp_b,
    const float* __restrict__ lmp_w, const float* __restrict__ lmp_b,
    const float* __restrict__ fc1_w, const float* __restrict__ fc1_b,
    const float* __restrict__ fc2_w, const float* __restrict__ fc2_b,
    const float* __restrict__ fc3_w, const float* __restrict__ fc3_b,
    const float* __restrict__ feat_ws, const float* __restrict__ dfeat_ws,
    float* __restrict__ out)
{
    __shared__ float na[240];     // nodes_all [5][4][12]
    __shared__ float msg[240];
    __shared__ float lastb[240];
    __shared__ __align__(16) float x[360];
    __shared__ __align__(16) float h1[180];
    __shared__ float h2[60];
    const int b = blockIdx.x, t = threadIdx.x;

    if (t < 240) {
        const int k = t % 12, m = (t / 12) % 4, f = t / 48;
        na[t] = (k < 6) ? feat_ws[b*120 + f*24 + m*6 + k]
                        : pos[b*120 + f*24 + m*6 + (k - 6)];
    }
    __syncthreads();
    if (t < 240) {
        const int d = t % 12, base = (t / 12) * 12;
        float s1 = fmp_b[d], s2 = lmp_b[d];
        #pragma unroll
        for (int k = 0; k < 12; ++k) {
            const float v = na[base + k];
            s1 = fmaf(v, fmp_w[d*12 + k], s1);
            s2 = fmaf(v, lmp_w[d*12 + k], s2);
        }
        msg[t] = s1; lastb[t] = s2;
    }
    __syncthreads();
    if (t < 240) {
        const int d = t % 12, n = (t / 12) % 4, f = t / 48;
        float s = 0.f;
        #pragma unroll
        for (int m = 0; m < 4; ++m)
            s = fmaf(attmap[b*80 + f*16 + m*4 + n], msg[f*48 + m*12 + d], s);
        if (f > 0) s += lastb[(f-1)*48 + n*12 + d];
        x[(f*4 + n)*18 + d] = s;
    }
    if (t < 120) {
        const int j = t % 6, n = (t / 6) % 4, f = t / 24;
        x[(f*4 + n)*18 + 12 + j] = dfeat_ws[b*120 + f*24 + n*6 + j];
    }
    __syncthreads();
    if (t < 180) {
        const float4* wr = (const float4*)(fc1_w + t * 360);
        const float4* xs = (const float4*)x;
        float s = fc1_b[t];
        #pragma unroll 10
        for (int k = 0; k < 90; ++k) {
            const float4 w4 = wr[k]; const float4 x4 = xs[k];
            s = fmaf(w4.x, x4.x, s); s = fmaf(w4.y, x4.y, s);
            s = fmaf(w4.z, x4.z, s); s = fmaf(w4.w, x4.w, s);
        }
        h1[t] = fmaxf(s, 0.f);
    }
    __syncthreads();
    if (t < 60) {
        const float4* wr = (const float4*)(fc2_w + t * 180);
        const float4* hs = (const float4*)h1;
        float s = fc2_b[t];
        #pragma unroll
        for (int k = 0; k < 45; ++k) {
            const float4 w4 = wr[k]; const float4 x4 = hs[k];
            s = fmaf(w4.x, x4.x, s); s = fmaf(w4.y, x4.y, s);
            s = fmaf(w4.z, x4.z, s); s = fmaf(w4.w, x4.w, s);
        }
        h2[t] = fmaxf(s, 0.f);
    }
    __syncthreads();
    if (t < 6) {
        float s = fc3_b[t];
        #pragma unroll
        for (int k = 0; k < 60; ++k) s = fmaf(h2[k], fc3_w[t*60 + k], s);
        out[b*6 + t] = s;
    }
}

extern "C" void kernel_launch(void* const* d_in, const int* in_sizes, int n_in,
                              void* d_out, int out_size, void* d_ws, size_t ws_size,
                              hipStream_t stream) {
    const float* nodes  = (const float*)d_in[0];
    const float* pos    = (const float*)d_in[1];
    const float* attmap = (const float*)d_in[2];
    const float* depths = (const float*)d_in[3];
    const float* c1w = (const float*)d_in[4],  *c1b = (const float*)d_in[5];
    const float* c2w = (const float*)d_in[6],  *c2b = (const float*)d_in[7];
    const float* lw  = (const float*)d_in[8],  *lb  = (const float*)d_in[9];
    const float* d1w = (const float*)d_in[10], *d1b = (const float*)d_in[11];
    const float* d2w = (const float*)d_in[12], *d2b = (const float*)d_in[13];
    const float* dlw = (const float*)d_in[14], *dlb = (const float*)d_in[15];
    const float* fmpw = (const float*)d_in[16], *fmpb = (const float*)d_in[17];
    const float* lmpw = (const float*)d_in[18], *lmpb = (const float*)d_in[19];
    const float* fc1w = (const float*)d_in[20], *fc1b = (const float*)d_in[21];
    const float* fc2w = (const float*)d_in[22], *fc2b = (const float*)d_in[23];
    const float* fc3w = (const float*)d_in[24], *fc3b = (const float*)d_in[25];

    // ws: pool1 [640][4108] = 10.52 MB (channel-minor, padded), then feats
    float* pool1_ws = (float*)d_ws;
    float* feat_ws  = pool1_ws + (size_t)640 * P1_STRIDE;
    float* dfeat_ws = feat_ws + 1920;

    dim3 g1(19, 640);   // 19 bands of 2 pooled rows x 640 images
    conv1_kernel<<<g1, 256, 0, stream>>>(
        nodes, depths, c1w, c1b, d1w, d1b, pool1_ws);

    conv2_kernel<<<640, 64, 0, stream>>>(
        pool1_ws, c2w, c2b, lw, lb, d2w, d2b, dlw, dlb, feat_ws, dfeat_ws);

    head_kernel<<<16, 256, 0, stream>>>(
        pos, attmap, fmpw, fmpb, lmpw, lmpb,
        fc1w, fc1b, fc2w, fc2b, fc3w, fc3b,
        feat_ws, dfeat_ws, (float*)d_out);
}

// Round 3
// 441.224 us; speedup vs baseline: 1.2669x; 1.2669x over previous
//
#include <hip/hip_runtime.h>

#define IN_W 224
#define IMG_CH (224*224)        // 50176
#define IMG_SZ (3*IMG_CH)       // 150528
#define P1 37
#define P1SZ (P1*P1)            // 1369
#define P1_STRIDE 4108          // 3*1369 = 4107, +1 pad -> float4-aligned per image

// ---------------------------------------------------------------------------
// Kernel 1: conv1(3x3,s2) + maxpool3 + relu.
// Block = (band of 2 pooled rows, image). Stage 13 input rows x 224 x 3ch
// into LDS via global_load_lds (16B DMA, no VGPR round-trip -> no spills).
// Thread = (site, out-ch): 222 active threads, 243 FMA each, compute from LDS.
// Output layout: [img][site][ch] channel-minor -> contiguous 888B store run.
// ---------------------------------------------------------------------------
__global__ __launch_bounds__(256, 4) void conv1_kernel(
    const float* __restrict__ nodes, const float* __restrict__ depths,
    const float* __restrict__ c1w, const float* __restrict__ c1b,
    const float* __restrict__ d1w, const float* __restrict__ d1b,
    float* __restrict__ pool1_ws)
{
    // 9 iters x 256 lanes x 16B = 36864 B (covers 2184 used float4 + clamp pad)
    __shared__ __align__(16) float lds[9216];

    const int band = blockIdx.x;          // 0..18
    const int img  = blockIdx.y;          // 0..639
    const int t    = threadIdx.x;

    const float* in; const float* w1g; const float* b1g;
    if (img < 320) { in = nodes  + (size_t)img         * IMG_SZ; w1g = c1w; b1g = c1b; }
    else           { in = depths + (size_t)(img - 320) * IMG_SZ; w1g = d1w; b1g = d1b; }

    const int py0   = 2 * band;
    const int nsr   = (py0 + 1 < P1) ? 2 : 1;   // site rows in this band
    const int nrows = 6 * nsr + 1;              // 13 or 7 input rows
    const int row0  = 12 * band;

    const int lane = t & 63, wv = t >> 6;

    // ---- stage: global -> LDS DMA, 16B/lane, linear LDS dest ----
    // f indexes float4 tiles: f = ch*728 + rr*56 + cc  (728 = 13*56)
    #pragma unroll
    for (int i = 0; i < 9; ++i) {
        const int fbase = i * 256 + wv * 64;         // wave-uniform
        int f = fbase + lane;
        f = (f < 2184) ? f : 2183;                   // clamp tail (dup reads, no OOB)
        const int ch = f / 728;
        int rr = (f - ch * 728) / 56;
        const int cc = f - ch * 728 - rr * 56;
        rr = (rr < nrows) ? rr : (nrows - 1);        // clamp short band rows
        const float* gp = in + ch * IMG_CH + (row0 + rr) * IN_W + cc * 4;
        __builtin_amdgcn_global_load_lds(
            (const __attribute__((address_space(1))) unsigned int*)gp,
            (__attribute__((address_space(3))) unsigned int*)&lds[fbase * 4],
            16, 0, 0);
    }

    // per-thread weights for its out-channel (overlaps with DMA)
    const int c = t % 3, s = t / 3;
    float w[27];
    #pragma unroll
    for (int k = 0; k < 27; ++k) w[k] = w1g[c * 27 + k];
    const float bv = b1g[c];

    __syncthreads();   // compiler emits vmcnt(0) drain before barrier

    // ---- compute: LDS layout = [ch][13][224] floats ----
    const int nsites = nsr * 37;
    if (s < nsites) {
        const int dy = s / 37, px = s - dy * 37;
        float acc[9];
        #pragma unroll
        for (int q = 0; q < 9; ++q) acc[q] = bv;

        #pragma unroll
        for (int ic = 0; ic < 3; ++ic) {
            const float* base = &lds[(ic * 13 + 6 * dy) * 224 + 6 * px];
            #pragma unroll
            for (int r = 0; r < 7; ++r) {
                const float* rp = base + r * 224;       // 8B-aligned (even offs)
                const float2 a0 = *(const float2*)(rp);
                const float2 a1 = *(const float2*)(rp + 2);
                const float2 a2 = *(const float2*)(rp + 4);
                float row[7];
                row[0] = a0.x; row[1] = a0.y; row[2] = a1.x; row[3] = a1.y;
                row[4] = a2.x; row[5] = a2.y; row[6] = rp[6];
                #pragma unroll
                for (int ky = 0; ky < 3; ++ky) {
                    const int u = r - 2 * ky;           // compile-time after unroll
                    if (u < 0 || u > 2) continue;
                    #pragma unroll
                    for (int kx = 0; kx < 3; ++kx)
                        #pragma unroll
                        for (int vv = 0; vv < 3; ++vv)
                            acc[ky*3+kx] = fmaf(row[2*kx + vv],
                                                w[ic*9 + u*3 + vv],
                                                acc[ky*3+kx]);
                }
            }
        }
        float m = acc[0];
        #pragma unroll
        for (int q = 1; q < 9; ++q) m = fmaxf(m, acc[q]);
        // channel-minor: lanes t = 3*s + c write consecutive addresses
        pool1_ws[(size_t)img * P1_STRIDE + (py0 * 37 + s) * 3 + c] = fmaxf(m, 0.f);
    }
}

// ---------------------------------------------------------------------------
// Kernel 2: conv2(3->1,3x3,s2) + maxpool3 + relu + linear 36->6, per image.
// Stage pool1 image (16.4 KB) into LDS with coalesced float4, compute there.
// pool1 layout is [site][3] channel-minor.
// ---------------------------------------------------------------------------
__global__ __launch_bounds__(256) void conv2_kernel(
    const float* __restrict__ pool1_ws,
    const float* __restrict__ c2w, const float* __restrict__ c2b,
    const float* __restrict__ lw,  const float* __restrict__ lb,
    const float* __restrict__ d2w, const float* __restrict__ d2b,
    const float* __restrict__ dlw, const float* __restrict__ dlb,
    float* __restrict__ feat_ws, float* __restrict__ dfeat_ws)
{
    __shared__ __align__(16) float p1s[P1_STRIDE];   // 4108 floats
    __shared__ float pool2[36];
    const int img = blockIdx.x;
    const int t = threadIdx.x;
    const float *w2, *b2, *lwp, *lbp; float* outp;
    if (img < 320) { w2 = c2w; b2 = c2b; lwp = lw;  lbp = lb;  outp = feat_ws  + img * 6; }
    else           { w2 = d2w; b2 = d2b; lwp = dlw; lbp = dlb; outp = dfeat_ws + (img - 320) * 6; }

    const float4* src = (const float4*)(pool1_ws + (size_t)img * P1_STRIDE);
    #pragma unroll
    for (int i = 0; i < 5; ++i) {
        const int f = t + i * 256;
        if (f < P1_STRIDE / 4) ((float4*)p1s)[f] = src[f];
    }
    __syncthreads();

    if (t < 36) {
        const int qy = t / 6, qx = t - qy * 6;
        float acc[9];
        const float bvv = b2[0];
        #pragma unroll
        for (int q = 0; q < 9; ++q) acc[q] = bvv;
        #pragma unroll
        for (int r = 0; r < 7; ++r) {
            // 7 sites x 3 ch = 21 contiguous floats
            const float* rp = &p1s[((6 * qy + r) * 37 + 6 * qx) * 3];
            float buf[21];
            #pragma unroll
            for (int j = 0; j < 21; ++j) buf[j] = rp[j];
            #pragma unroll
            for (int ky = 0; ky < 3; ++ky) {
                const int u = r - 2 * ky;
                if (u < 0 || u > 2) continue;
                #pragma unroll
                for (int kx = 0; kx < 3; ++kx)
                    #pragma unroll
                    for (int vv = 0; vv < 3; ++vv)
                        #pragma unroll
                        for (int ic = 0; ic < 3; ++ic)
                            acc[ky*3+kx] = fmaf(buf[(2*kx + vv) * 3 + ic],
                                                w2[ic*9 + u*3 + vv],
                                                acc[ky*3+kx]);
            }
        }
        float m = acc[0];
        #pragma unroll
        for (int q = 1; q < 9; ++q) m = fmaxf(m, acc[q]);
        pool2[t] = fmaxf(m, 0.f);
    }
    __syncthreads();
    if (t < 6) {
        float sacc = lbp[t];
        #pragma unroll
        for (int k = 0; k < 36; ++k) sacc = fmaf(pool2[k], lwp[t*36 + k], sacc);
        outp[t] = sacc;
    }
}

// ---------------------------------------------------------------------------
// Head: message passing + fc1/fc2/fc3 (unchanged).
// ---------------------------------------------------------------------------
__global__ __launch_bounds__(256) void head_kernel(
    const float* __restrict__ pos, const float* __restrict__ attmap,
    const float* __restrict__ fmp_w, const float* __restrict__ fmp_b,
    const float* __restrict__ lmp_w, const float* __restrict__ lmp_b,
    const float* __restrict__ fc1_w, const float* __restrict__ fc1_b,
    const float* __restrict__ fc2_w, const float* __restrict__ fc2_b,
    const float* __restrict__ fc3_w, const float* __restrict__ fc3_b,
    const float* __restrict__ feat_ws, const float* __restrict__ dfeat_ws,
    float* __restrict__ out)
{
    __shared__ float na[240];     // nodes_all [5][4][12]
    __shared__ float msg[240];
    __shared__ float lastb[240];
    __shared__ __align__(16) float x[360];
    __shared__ __align__(16) float h1[180];
    __shared__ float h2[60];
    const int b = blockIdx.x, t = threadIdx.x;

    if (t < 240) {
        const int k = t % 12, m = (t / 12) % 4, f = t / 48;
        na[t] = (k < 6) ? feat_ws[b*120 + f*24 + m*6 + k]
                        : pos[b*120 + f*24 + m*6 + (k - 6)];
    }
    __syncthreads();
    if (t < 240) {
        const int d = t % 12, base = (t / 12) * 12;
        float s1 = fmp_b[d], s2 = lmp_b[d];
        #pragma unroll
        for (int k = 0; k < 12; ++k) {
            const float v = na[base + k];
            s1 = fmaf(v, fmp_w[d*12 + k], s1);
            s2 = fmaf(v, lmp_w[d*12 + k], s2);
        }
        msg[t] = s1; lastb[t] = s2;
    }
    __syncthreads();
    if (t < 240) {
        const int d = t % 12, n = (t / 12) % 4, f = t / 48;
        float s = 0.f;
        #pragma unroll
        for (int m = 0; m < 4; ++m)
            s = fmaf(attmap[b*80 + f*16 + m*4 + n], msg[f*48 + m*12 + d], s);
        if (f > 0) s += lastb[(f-1)*48 + n*12 + d];
        x[(f*4 + n)*18 + d] = s;
    }
    if (t < 120) {
        const int j = t % 6, n = (t / 6) % 4, f = t / 24;
        x[(f*4 + n)*18 + 12 + j] = dfeat_ws[b*120 + f*24 + n*6 + j];
    }
    __syncthreads();
    if (t < 180) {
        const float4* wr = (const float4*)(fc1_w + t * 360);
        const float4* xs = (const float4*)x;
        float s = fc1_b[t];
        #pragma unroll 10
        for (int k = 0; k < 90; ++k) {
            const float4 w4 = wr[k]; const float4 x4 = xs[k];
            s = fmaf(w4.x, x4.x, s); s = fmaf(w4.y, x4.y, s);
            s = fmaf(w4.z, x4.z, s); s = fmaf(w4.w, x4.w, s);
        }
        h1[t] = fmaxf(s, 0.f);
    }
    __syncthreads();
    if (t < 60) {
        const float4* wr = (const float4*)(fc2_w + t * 180);
        const float4* hs = (const float4*)h1;
        float s = fc2_b[t];
        #pragma unroll
        for (int k = 0; k < 45; ++k) {
            const float4 w4 = wr[k]; const float4 x4 = hs[k];
            s = fmaf(w4.x, x4.x, s); s = fmaf(w4.y, x4.y, s);
            s = fmaf(w4.z, x4.z, s); s = fmaf(w4.w, x4.w, s);
        }
        h2[t] = fmaxf(s, 0.f);
    }
    __syncthreads();
    if (t < 6) {
        float s = fc3_b[t];
        #pragma unroll
        for (int k = 0; k < 60; ++k) s = fmaf(h2[k], fc3_w[t*60 + k], s);
        out[b*6 + t] = s;
    }
}

extern "C" void kernel_launch(void* const* d_in, const int* in_sizes, int n_in,
                              void* d_out, int out_size, void* d_ws, size_t ws_size,
                              hipStream_t stream) {
    const float* nodes  = (const float*)d_in[0];
    const float* pos    = (const float*)d_in[1];
    const float* attmap = (const float*)d_in[2];
    const float* depths = (const float*)d_in[3];
    const float* c1w = (const float*)d_in[4],  *c1b = (const float*)d_in[5];
    const float* c2w = (const float*)d_in[6],  *c2b = (const float*)d_in[7];
    const float* lw  = (const float*)d_in[8],  *lb  = (const float*)d_in[9];
    const float* d1w = (const float*)d_in[10], *d1b = (const float*)d_in[11];
    const float* d2w = (const float*)d_in[12], *d2b = (const float*)d_in[13];
    const float* dlw = (const float*)d_in[14], *dlb = (const float*)d_in[15];
    const float* fmpw = (const float*)d_in[16], *fmpb = (const float*)d_in[17];
    const float* lmpw = (const float*)d_in[18], *lmpb = (const float*)d_in[19];
    const float* fc1w = (const float*)d_in[20], *fc1b = (const float*)d_in[21];
    const float* fc2w = (const float*)d_in[22], *fc2b = (const float*)d_in[23];
    const float* fc3w = (const float*)d_in[24], *fc3b = (const float*)d_in[25];

    // ws: pool1 [640][4108] = 10.52 MB (channel-minor, padded), then feats
    float* pool1_ws = (float*)d_ws;
    float* feat_ws  = pool1_ws + (size_t)640 * P1_STRIDE;
    float* dfeat_ws = feat_ws + 1920;

    dim3 g1(19, 640);   // 19 bands of 2 pooled rows x 640 images
    conv1_kernel<<<g1, 256, 0, stream>>>(
        nodes, depths, c1w, c1b, d1w, d1b, pool1_ws);

    conv2_kernel<<<640, 256, 0, stream>>>(
        pool1_ws, c2w, c2b, lw, lb, d2w, d2b, dlw, dlb, feat_ws, dfeat_ws);

    head_kernel<<<16, 256, 0, stream>>>(
        pos, attmap, fmpw, fmpb, lmpw, lmpb,
        fc1w, fc1b, fc2w, fc2b, fc3w, fc3b,
        feat_ws, dfeat_ws, (float*)d_out);
}